// Round 11
// baseline (246.557 us; speedup 1.0000x reference)
//
#include <hip/hip_runtime.h>
#include <hip/hip_bf16.h>

// Problem constants (B=8, C=64, H=128, W=256)
#define HW_ 32768          // H*W
#define OUTHALF 16777216ULL
#define SMEM_BYTES 81920

typedef short short8  __attribute__((ext_vector_type(8)));
typedef short short4v __attribute__((ext_vector_type(4)));
typedef float f32x4   __attribute__((ext_vector_type(4)));
typedef unsigned int uint2v __attribute__((ext_vector_type(2)));
typedef unsigned int uint4v __attribute__((ext_vector_type(4)));

__device__ __forceinline__ unsigned short f2bf(float f) {
  unsigned u = __builtin_bit_cast(unsigned, f);
  u += 0x7fffu + ((u >> 16) & 1u);          // RNE; setup kernel only
  return (unsigned short)(u >> 16);
}
// native cast — compiler packs pairs into v_cvt_pk_bf16_f32 (R7-verified)
__device__ __forceinline__ short f2bfn(float f) {
  __hip_bfloat16 h = __float2bfloat16(f);
  return __builtin_bit_cast(short, h);
}
__device__ __forceinline__ unsigned pkw(float lo, float hi) {
  unsigned short a = (unsigned short)f2bfn(lo), b = (unsigned short)f2bfn(hi);
  return ((unsigned)b << 16) | (unsigned)a;
}
__device__ __forceinline__ char* swz(char* base, int row, int colByte) {
  // 128-byte rows; XOR bits 4-6 — proven for b128 reads (R1..R10)
  return base + row * 128 + (colByte ^ ((row & 7) << 4));
}
__device__ __forceinline__ char* swzV(char* base, int row, int colByte) {
  // 128-byte rows; XOR bits 5-6 only — disjoint from b64 col bits (3-4),
  // gives uniform bank spread for the K16 bv reads
  return base + row * 128 + (colByte ^ ((row & 3) << 5));
}
__device__ __forceinline__ f32x4 zero4() { f32x4 z = {0.f, 0.f, 0.f, 0.f}; return z; }

// In-register g-group transpose (R6-R10 verified). C-layout -> K32 A/B-fragment.
// Used once for the Q~ fragments.
__device__ __forceinline__ void xpose(const f32x4 (&p)[4], int g,
                                      short8& f0, short8& f1) {
  unsigned W00 = pkw(p[0][0], p[0][1]), W01 = pkw(p[0][2], p[0][3]);
  unsigned W10 = pkw(p[1][0], p[1][1]), W11 = pkw(p[1][2], p[1][3]);
  unsigned W20 = pkw(p[2][0], p[2][1]), W21 = pkw(p[2][2], p[2][3]);
  unsigned W30 = pkw(p[3][0], p[3][1]), W31 = pkw(p[3][2], p[3][3]);
  const bool h2 = (g & 2) != 0;
  unsigned SA0 = h2 ? W10 : W00, SA1 = h2 ? W11 : W01;
  unsigned SA2 = h2 ? W30 : W20, SA3 = h2 ? W31 : W21;
  unsigned SB0 = h2 ? W00 : W10, SB1 = h2 ? W01 : W11;
  unsigned SB2 = h2 ? W20 : W30, SB3 = h2 ? W21 : W31;
  unsigned ra0 = __shfl_xor((int)SA0, 16), ra1 = __shfl_xor((int)SA1, 16);
  unsigned ra2 = __shfl_xor((int)SA2, 16), ra3 = __shfl_xor((int)SA3, 16);
  unsigned rb0 = __shfl_xor((int)SB0, 32), rb1 = __shfl_xor((int)SB1, 32);
  unsigned rb2 = __shfl_xor((int)SB2, 32), rb3 = __shfl_xor((int)SB3, 32);
  unsigned rc0 = __shfl_xor((int)SB0, 48), rc1 = __shfl_xor((int)SB1, 48);
  unsigned rc2 = __shfl_xor((int)SB2, 48), rc3 = __shfl_xor((int)SB3, 48);
  unsigned a0 = g==0 ? SA0 : g==1 ? rc0 : g==2 ? rb0 : ra0;
  unsigned a1 = g==0 ? SA1 : g==1 ? rc1 : g==2 ? rb1 : ra1;
  unsigned a2 = g==0 ? SA2 : g==1 ? rc2 : g==2 ? rb2 : ra2;
  unsigned a3 = g==0 ? SA3 : g==1 ? rc3 : g==2 ? rb3 : ra3;
  unsigned b0 = g==3 ? SA0 : g==2 ? rc0 : g==1 ? rb0 : ra0;
  unsigned b1 = g==3 ? SA1 : g==2 ? rc1 : g==1 ? rb1 : ra1;
  unsigned b2 = g==3 ? SA2 : g==2 ? rc2 : g==1 ? rb2 : ra2;
  unsigned b3 = g==3 ? SA3 : g==2 ? rc3 : g==1 ? rb3 : ra3;
  uint4v u0 = {a0, a1, b0, b1};
  uint4v u1 = {a2, a3, b2, b3};
  f0 = __builtin_bit_cast(short8, u0);
  f1 = __builtin_bit_cast(short8, u1);
}

// ---------------- setup: Mbt[y][x] = sum_o Wq'[o][x] Wk'[o][y] (bf16), u[y]
__global__ void pam_setup(const float* __restrict__ Wq, const float* __restrict__ bq,
                          const float* __restrict__ gq, const float* __restrict__ betaq,
                          const float* __restrict__ mq, const float* __restrict__ vq,
                          const float* __restrict__ Wk, const float* __restrict__ gk,
                          const float* __restrict__ vk,
                          short* __restrict__ Mbt, float* __restrict__ u) {
  int blk = blockIdx.x, tid = threadIdx.x;
  if (blk < 16) {
    int entry = blk * 256 + tid;
    int y = entry >> 6, x = entry & 63;
    float acc = 0.f;
    for (int o = 0; o < 64; ++o) {
      float sq = gq[o] * rsqrtf(vq[o] + 1e-5f);
      float sk = gk[o] * rsqrtf(vk[o] + 1e-5f);
      acc += Wq[o * 64 + x] * sq * Wk[o * 64 + y] * sk;
    }
    Mbt[y * 64 + x] = (short)f2bf(acc);
  } else if (tid < 64) {
    int y = tid;
    float acc = 0.f;
    for (int o = 0; o < 64; ++o) {
      float sq = gq[o] * rsqrtf(vq[o] + 1e-5f);
      float sk = gk[o] * rsqrtf(vk[o] + 1e-5f);
      float bqq = bq[o] * sq + betaq[o] - mq[o] * sq;
      acc += bqq * Wk[o * 64 + y] * sk;
    }
    u[y] = acc;
  }
}

// ---------------- main: one block per (b,h,dir); 1024 thr, 16 waves x 16 q;
// LDS 80KB -> 2 blocks/CU (32 waves). V double-buffered, 1 barrier/vt.
__global__ __launch_bounds__(1024, 8) void pam_main(
    const float* __restrict__ fl, const float* __restrict__ fr,
    const short* __restrict__ Mbt, const float* __restrict__ uvec,
    float* __restrict__ out) {
  extern __shared__ __align__(16) char sm[];
  char* XLt = sm;                     // [256 pos][64 c] bf16 swizzled (128B rows)
  char* XRt = sm + 32768;
  char* Xn  = sm + 65536;             // [2 buf][64 c][64 v] bf16, swzV rows

  const int tid  = threadIdx.x;
  const int lane = tid & 63;
  const int wave = tid >> 6;          // 0..15
  const int l15  = lane & 15;
  const int g    = lane >> 4;
  const int bh   = blockIdx.x >> 1;
  const int at   = blockIdx.x & 1;    // direction of this block
  const int bb   = bh >> 7;
  const int hh   = bh & 127;
  const int rowOff = hh * 256;
  const int base_b = bb * 64;
  const int w0   = wave * 16;         // this wave's 16 query rows

  // ---- V staging role: every thread stages 4 v of one channel ----
  const int vcc = tid >> 4;           // channel 0..63
  const int vv4 = (tid & 15) * 4;     // 4 positions
  const float* srcv = at ? fl : fr;   // kv/value side
  const float* vbase = srcv + (size_t)(base_b + vcc) * HW_ + rowOff + vv4;

  f32x4 A = *(const f32x4*)vbase;     // V tile 0 (independent of LDS)

  // ---- stage XLt + XRt (f32 global -> bf16 LDS, [pos][chan]) ----
  #pragma unroll
  for (int it = 0; it < 8; ++it) {
    int unit = it * 1024 + tid;       // 0..8191
    int tensor = unit >> 12;
    int rem = unit & 4095;
    int cq = rem >> 8;                // channel quad 0..15
    int p  = rem & 255;               // position
    const float* s = (tensor ? fr : fl) + (size_t)(base_b + cq * 4) * HW_ + rowOff + p;
    float v0 = s[0], v1 = s[HW_], v2 = s[2 * HW_], v3 = s[3 * HW_];
    short4v pk;
    pk[0] = f2bfn(v0); pk[1] = f2bfn(v1);
    pk[2] = f2bfn(v2); pk[3] = f2bfn(v3);
    *(short4v*)swz(tensor ? XRt : XLt, p, cq * 8) = pk;
  }
  // ---- V tile 0 -> buf 0 ----
  {
    short4v pk;
    pk[0] = f2bfn(A[0]); pk[1] = f2bfn(A[1]);
    pk[2] = f2bfn(A[2]); pk[3] = f2bfn(A[3]);
    *(short4v*)swzV(Xn, vcc, vv4 * 2) = pk;
  }
  A = *(const f32x4*)(vbase + 64);    // prefetch V tile 1
  __syncthreads();                    // slabs + V buf0 visible

  char* Xq  = at ? XRt : XLt;         // query side
  char* Xkv = at ? XLt : XRt;         // key/value side (S-GEMM A operand)

  // ---- Q^ = M^T Xq + u for this wave's 16 rows; one-time xpose ----
  short8 bq_[2];
  {
    short8 xb0 = *(const short8*)swz(Xq, w0 + l15, (8 * g) * 2);
    short8 xb1 = *(const short8*)swz(Xq, w0 + l15, (32 + 8 * g) * 2);
    f32x4 qa[4];
    #pragma unroll
    for (int mi = 0; mi < 4; ++mi) {
      qa[mi] = zero4();
      short8 am0 = *(const short8*)(Mbt + (mi * 16 + l15) * 64 + 8 * g);
      short8 am1 = *(const short8*)(Mbt + (mi * 16 + l15) * 64 + 32 + 8 * g);
      qa[mi] = __builtin_amdgcn_mfma_f32_16x16x32_bf16(am0, xb0, qa[mi], 0, 0, 0);
      qa[mi] = __builtin_amdgcn_mfma_f32_16x16x32_bf16(am1, xb1, qa[mi], 0, 0, 0);
      f32x4 uv = *(const f32x4*)(uvec + mi * 16 + 4 * g);
      #pragma unroll
      for (int r = 0; r < 4; ++r) qa[mi][r] += uv[r];
    }
    xpose(qa, g, bq_[0], bq_[1]);
  }

  // ---- accumulators (16 q/wave: 4 f32x4) ----
  f32x4 acc_o[4];
  #pragma unroll
  for (int j = 0; j < 4; ++j) acc_o[j] = zero4();
  float dacc = 0.f;

  #pragma unroll
  for (int vt = 0; vt < 4; ++vt) {
    // ---- stage V(vt+1) into the other buffer; issue load for vt+2 ----
    if (vt < 3) {
      short4v pk;
      pk[0] = f2bfn(A[0]); pk[1] = f2bfn(A[1]);
      pk[2] = f2bfn(A[2]); pk[3] = f2bfn(A[3]);
      *(short4v*)swzV(Xn + ((vt + 1) & 1) * 8192, vcc, vv4 * 2) = pk;
      if (vt < 2) A = *(const f32x4*)(vbase + (vt + 2) * 64);
    }
    char* XnB = Xn + (vt & 1) * 8192;

    // ---- fused per-mi: S-GEMM (K32) -> exp -> pack -> PV (K16) ----
    #pragma unroll
    for (int mi = 0; mi < 4; ++mi) {
      short8 af0 = *(const short8*)swz(Xkv, vt * 64 + mi * 16 + l15, (8 * g) * 2);
      short8 af1 = *(const short8*)swz(Xkv, vt * 64 + mi * 16 + l15, (32 + 8 * g) * 2);
      f32x4 ps = zero4();
      ps = __builtin_amdgcn_mfma_f32_16x16x32_bf16(af0, bq_[0], ps, 0, 0, 0);
      ps = __builtin_amdgcn_mfma_f32_16x16x32_bf16(af1, bq_[1], ps, 0, 0, 0);
      #pragma unroll
      for (int r = 0; r < 4; ++r)
        ps[r] = __expf(ps[r] * 0.015625f);
      dacc += ps[0] + ps[1] + ps[2] + ps[3];
      uint2v pw;
      pw[0] = pkw(ps[0], ps[1]);
      pw[1] = pkw(ps[2], ps[3]);
      short4v pa = __builtin_bit_cast(short4v, pw);
      #pragma unroll
      for (int nj2 = 0; nj2 < 4; ++nj2) {
        short4v bv = *(const short4v*)swzV(XnB, nj2 * 16 + l15, (mi * 16 + 4 * g) * 2);
        acc_o[nj2] = __builtin_amdgcn_mfma_f32_16x16x16bf16_1k(pa, bv, acc_o[nj2], 0, 0, 0);
      }
    }
    if (vt < 3) __syncthreads();      // V(vt+1) visible / buf(vt) free next round
  } // vt

  // ---- D redistribute via shuffles (no LDS) + epilogue ----
  dacc += __shfl_xor(dacc, 16); dacc += __shfl_xor(dacc, 32);
  float dinv = __builtin_amdgcn_rcpf(dacc);   // lane(l15,g) holds 1/D[w0+l15]
  f32x4 rd;
  #pragma unroll
  for (int r = 0; r < 4; ++r) rd[r] = __shfl(dinv, 4 * g + r);
  float* outp = out + (at ? OUTHALF : 0) + (size_t)base_b * HW_ + rowOff;
  #pragma unroll
  for (int nj2 = 0; nj2 < 4; ++nj2) {
    int c = nj2 * 16 + l15;
    f32x4 v;
    v[0] = acc_o[nj2][0] * rd[0];
    v[1] = acc_o[nj2][1] * rd[1];
    v[2] = acc_o[nj2][2] * rd[2];
    v[3] = acc_o[nj2][3] * rd[3];
    *(f32x4*)(outp + (size_t)c * HW_ + w0 + 4 * g) = v;
  }
}

extern "C" void kernel_launch(void* const* d_in, const int* in_sizes, int n_in,
                              void* d_out, int out_size, void* d_ws, size_t ws_size,
                              hipStream_t stream) {
  (void)in_sizes; (void)n_in; (void)out_size; (void)ws_size;
  const float* fl    = (const float*)d_in[0];
  const float* fr    = (const float*)d_in[1];
  const float* Wq    = (const float*)d_in[2];
  const float* bq    = (const float*)d_in[3];
  const float* gq    = (const float*)d_in[4];
  const float* betaq = (const float*)d_in[5];
  const float* mq    = (const float*)d_in[6];
  const float* vq    = (const float*)d_in[7];
  const float* Wk    = (const float*)d_in[8];
  const float* gk    = (const float*)d_in[10];
  const float* vk    = (const float*)d_in[13];
  short* Mbt = (short*)d_ws;
  float* u   = (float*)((char*)d_ws + 8192);
  float* out = (float*)d_out;

  hipFuncSetAttribute((const void*)pam_main,
                      hipFuncAttributeMaxDynamicSharedMemorySize, SMEM_BYTES);
  pam_setup<<<17, 256, 0, stream>>>(Wq, bq, gq, betaq, mq, vq, Wk, gk, vk, Mbt, u);
  pam_main<<<2048, 1024, SMEM_BYTES, stream>>>(fl, fr, Mbt, u, out);
}